// Round 6
// baseline (104.138 us; speedup 1.0000x reference)
//
#include <hip/hip_runtime.h>

// Problem constants (from reference setup_inputs)
static constexpr int B_ = 2, N_ = 2048, NL_ = 512, IN_C_ = 16, C_ = 32, H_ = 32;
static constexpr float R1SQ = (float)(0.07 * 0.07);   // (RADIUS*1)^2
static constexpr float R2SQ = (float)(0.14 * 0.14);   // (RADIUS*2)^2

typedef __attribute__((ext_vector_type(8))) short bf16x8;  // 8 bf16 = 4 VGPRs
typedef __attribute__((ext_vector_type(4))) float f32x4;   // 4 fp32 acc

// jax.nn.gelu(approximate=True) via identity 0.5x(1+tanh(z)) = x*(1 - 1/(exp(2z)+1)).
// v_rcp_f32 (1 ulp) instead of divide: absorbed by bf16 rounding downstream.
__device__ __forceinline__ float gelu_tanh(float x) {
    float z2 = 2.0f * 0.7978845608028654f * x * fmaf(0.044715f * x, x, 1.0f);
    float e = __expf(z2);
    float t = __builtin_amdgcn_rcpf(e + 1.0f);
    return x - x * t;
}

// fp32 -> bf16 bits, round-to-nearest-even (inputs finite)
__device__ __forceinline__ short f2bf(float x) {
    unsigned u = __float_as_uint(x);
    u += 0x7fffu + ((u >> 16) & 1u);
    return (short)(u >> 16);
}

// One block per (b, latent token i). 256 threads = 4 waves, fully fused.
// - Wave-private compaction (no LDS atomics), wave-private MLP loop with
//   ZERO block barriers inside (strans is per-wave; DS ops are in-order
//   within a wave, so the h2 transpose needs no __syncthreads).
// - Lift fused as K-padded (16->32) bf16 MFMA; its C/D layout matches
//   layer-3's, so the epilogue is pure register math. No workspace.
__global__ __launch_bounds__(256, 4)
void magno_fused(const float* __restrict__ x_coord,   // (B,N,2)
                 const float* __restrict__ lat,        // (NL,2)
                 const float* __restrict__ kW1, const float* __restrict__ kb1,
                 const float* __restrict__ kW2, const float* __restrict__ kb2,
                 const float* __restrict__ kW3, const float* __restrict__ kb3,
                 const float* __restrict__ pnd,        // (B,N,16)
                 const float* __restrict__ Wl,         // (16,32)
                 const float* __restrict__ bl,         // (32,)
                 float* __restrict__ out)              // (B,NL,32)
{
    __shared__ short sW2b[H_ * H_];                     // bf16-staged kW2
    __shared__ short sW3b[H_ * C_];                     // bf16-staged kW3
    __shared__ short sWlb[IN_C_ * C_];                  // bf16-staged W_lift
    __shared__ float sR0[H_], sR1[H_], sA1[H_];
    __shared__ unsigned jlist[4][512];                  // per-wave segments
    __shared__ __align__(16) short strans[4][64 * 40];  // per-wave bf16 transpose, pitch 40
    __shared__ float sred[4][C_];
    __shared__ int scnt[4][2];                          // per-wave {n, c1}

    const int tid  = threadIdx.x;
    const int lane = tid & 63;
    const int wid  = tid >> 6;
    const int qd   = lane >> 4;    // quad 0..3
    const int li   = lane & 15;
    const int bi = blockIdx.x;
    const int b = bi >> 9, i = bi & (NL_ - 1);
    const float xq0 = lat[2 * i], xq1 = lat[2 * i + 1];

    // per-lane channel biases (issued early; L2-warm broadcast lines)
    const float b2A = kb2[li], b2B = kb2[li + 16];
    const float b3A = kb3[li], b3B = kb3[li + 16];
    const float blA = bl[li],  blB = bl[li + 16];

    // ---- stage weights as bf16 into LDS (coalesced, converted once) ----
    for (int idx = tid; idx < H_ * H_; idx += 256) {
        sW2b[idx] = f2bf(kW2[idx]);
        sW3b[idx] = f2bf(kW3[idx]);
    }
    for (int idx = tid; idx < IN_C_ * C_; idx += 256) sWlb[idx] = f2bf(Wl[idx]);
    if (tid < H_) {
        sR0[tid] = kW1[tid];
        sR1[tid] = kW1[H_ + tid];
        sA1[tid] = fmaf(xq0, kW1[2 * H_ + tid], fmaf(xq1, kW1[3 * H_ + tid], kb1[tid]));
    }

    // ---- Pass A: wave-private ballot compaction over j in [512*wid, 512*(wid+1)) ----
    const float2* __restrict__ xc = (const float2*)(x_coord + (size_t)b * N_ * 2);
    const unsigned long long ltmask = (1ull << lane) - 1ull;
    float2 ys[8];
#pragma unroll
    for (int t = 0; t < 8; ++t) ys[t] = xc[512 * wid + 64 * t + lane];   // all in flight
    int cnt = 0, c1w = 0;
#pragma unroll
    for (int t = 0; t < 8; ++t) {
        float dy0 = ys[t].x - xq0, dy1 = ys[t].y - xq1;
        float d2 = dy0 * dy0 + dy1 * dy1;
        bool in2 = d2 <= R2SQ;
        bool in1 = d2 <= R1SQ;
        unsigned long long m2 = __ballot(in2);
        unsigned long long m1 = __ballot(in1);
        if (in2) {
            int pos = cnt + __popcll(m2 & ltmask);
            jlist[wid][pos] = (unsigned)(512 * wid + 64 * t + lane) | (in1 ? 0x80000000u : 0u);
        }
        cnt += __popcll(m2);   // wave-uniform
        c1w += __popcll(m1);
    }
    if (lane == 0) { scnt[wid][0] = cnt; scnt[wid][1] = c1w; }
    __syncthreads();   // covers weight staging + scnt

    const int n  = scnt[0][0] + scnt[1][0] + scnt[2][0] + scnt[3][0];
    const int c1 = scnt[0][1] + scnt[1][1] + scnt[2][1] + scnt[3][1];
    const float inv2 = 1.0f / (float)(n  > 0 ? n  : 1);
    const float inv1 = 1.0f / (float)(c1 > 0 ? c1 : 1);

    // W2/W3 B-fragments (verified 16x16x32 layout): B[k=qd*8+jj][n=li+16*nt]
    bf16x8 w2f[2], w3f[2];
#pragma unroll
    for (int nt = 0; nt < 2; ++nt) {
        int n0 = li + 16 * nt;
#pragma unroll
        for (int jj = 0; jj < 8; ++jj) {
            int k = qd * 8 + jj;
            w2f[nt][jj] = sW2b[k * H_ + n0];
            w3f[nt][jj] = sW3b[k * C_ + n0];
        }
    }

    short* tb = &strans[wid][0];
    const unsigned* __restrict__ jl = &jlist[wid][0];
    const float* __restrict__ pbase = pnd + (size_t)b * N_ * IN_C_;

    float accA = 0.0f, accB = 0.0f;   // channels li and li+16
    const bool pq = (qd < 2);

    // ---- Pass B: wave-private, no block barriers ----
    for (int base = 0; base < cnt; base += 64) {
        // entry indices for A-fragment rows (m = li within tile)
        int jm[4];
#pragma unroll
        for (int mt = 0; mt < 4; ++mt) {
            int e = base + 16 * mt + li;
            jm[mt] = (int)(jl[e & 511] & (unsigned)(N_ - 1));  // safe index; masked by w later
        }

        // pnd loads first (latency hides under gelu chain below)
        float4 pv[4][2];
        if (pq) {
#pragma unroll
            for (int mt = 0; mt < 4; ++mt) {
                const float4* p4 = (const float4*)(pbase + (size_t)jm[mt] * IN_C_ + qd * 8);
                pv[mt][0] = p4[0];
                pv[mt][1] = p4[1];
            }
        }
        float2 yv[4];
#pragma unroll
        for (int mt = 0; mt < 4; ++mt) yv[mt] = xc[jm[mt]];   // L1/L2-warm

        // W_lift B-fragment, K-padded 16->32 (k>=16 rows are zero; A side zero too)
        bf16x8 wlf[2];
#pragma unroll
        for (int nt = 0; nt < 2; ++nt) {
            int n0 = li + 16 * nt;
#pragma unroll
            for (int jj = 0; jj < 8; ++jj) {
                int k = qd * 8 + jj;
                wlf[nt][jj] = pq ? sWlb[k * C_ + n0] : (short)0;
            }
        }

        // lift MFMA: F = PND @ Wl  (D layout == layer-3's D layout)
        f32x4 accF[4][2];
#pragma unroll
        for (int mt = 0; mt < 4; ++mt) {
            bf16x8 paf;
            if (pq) {
                paf[0] = f2bf(pv[mt][0].x); paf[1] = f2bf(pv[mt][0].y);
                paf[2] = f2bf(pv[mt][0].z); paf[3] = f2bf(pv[mt][0].w);
                paf[4] = f2bf(pv[mt][1].x); paf[5] = f2bf(pv[mt][1].y);
                paf[6] = f2bf(pv[mt][1].z); paf[7] = f2bf(pv[mt][1].w);
            } else {
#pragma unroll
                for (int jj = 0; jj < 8; ++jj) paf[jj] = (short)0;
            }
            f32x4 z = {0.f, 0.f, 0.f, 0.f};
            accF[mt][0] = __builtin_amdgcn_mfma_f32_16x16x32_bf16(paf, wlf[0], z, 0, 0, 0);
            accF[mt][1] = __builtin_amdgcn_mfma_f32_16x16x32_bf16(paf, wlf[1], z, 0, 0, 0);
        }

        // layer 1 directly in A-fragment layout + layer 2 MFMA
        f32x4 acc2[4][2];
#pragma unroll
        for (int mt = 0; mt < 4; ++mt) {
            bf16x8 hfrag;
#pragma unroll
            for (int jj = 0; jj < 8; ++jj) {
                int k = qd * 8 + jj;
                float h = gelu_tanh(fmaf(yv[mt].x, sR0[k], fmaf(yv[mt].y, sR1[k], sA1[k])));
                hfrag[jj] = f2bf(h);
            }
            f32x4 z = {0.f, 0.f, 0.f, 0.f};
            acc2[mt][0] = __builtin_amdgcn_mfma_f32_16x16x32_bf16(hfrag, w2f[0], z, 0, 0, 0);
            acc2[mt][1] = __builtin_amdgcn_mfma_f32_16x16x32_bf16(hfrag, w2f[1], z, 0, 0, 0);
        }

        // h2 = gelu(acc2+b2) -> bf16 LDS [entry][hidden] (wave-private, in-order DS)
#pragma unroll
        for (int mt = 0; mt < 4; ++mt)
#pragma unroll
            for (int nt = 0; nt < 2; ++nt) {
                float bb = nt ? b2B : b2A;
                int hid = li + 16 * nt;
#pragma unroll
                for (int r = 0; r < 4; ++r) {
                    int entry = 16 * mt + 4 * qd + r;
                    tb[entry * 40 + hid] = f2bf(gelu_tanh(acc2[mt][nt][r] + bb));
                }
            }

        // layer 3: read A-fragments back (b128), MFMA
        f32x4 acc3[4][2];
#pragma unroll
        for (int mt = 0; mt < 4; ++mt) {
            bf16x8 h2 = *(const bf16x8*)&tb[(li + 16 * mt) * 40 + qd * 8];
            f32x4 z = {0.f, 0.f, 0.f, 0.f};
            acc3[mt][0] = __builtin_amdgcn_mfma_f32_16x16x32_bf16(h2, w3f[0], z, 0, 0, 0);
            acc3[mt][1] = __builtin_amdgcn_mfma_f32_16x16x32_bf16(h2, w3f[1], z, 0, 0, 0);
        }

        // epilogue: acc_c += w_e * (F_e[c]+bl[c]) * (KV_e[c]+b3[c])
        // D layout: row(entry-in-tile) = 4*qd + r, col(channel) = li + 16*nt
#pragma unroll
        for (int mt = 0; mt < 4; ++mt)
#pragma unroll
            for (int r = 0; r < 4; ++r) {
                int el = base + 16 * mt + 4 * qd + r;
                unsigned pk = jl[el & 511];
                float w = (el < cnt) ? (inv2 + ((pk & 0x80000000u) ? inv1 : 0.0f)) : 0.0f;
                accA = fmaf(w * (accF[mt][0][r] + blA), acc3[mt][0][r] + b3A, accA);
                accB = fmaf(w * (accF[mt][1][r] + blB), acc3[mt][1][r] + b3B, accB);
            }
    }

    // ---- reduce over quads (entries); channels already on lanes ----
    accA += __shfl_xor(accA, 16, 64);
    accA += __shfl_xor(accA, 32, 64);
    accB += __shfl_xor(accB, 16, 64);
    accB += __shfl_xor(accB, 32, 64);
    if (lane < 16) {
        sred[wid][li] = accA;
        sred[wid][li + 16] = accB;
    }
    __syncthreads();
    if (tid < C_)
        out[(size_t)bi * C_ + tid] = (sred[0][tid] + sred[1][tid]) + (sred[2][tid] + sred[3][tid]);
}

extern "C" void kernel_launch(void* const* d_in, const int* in_sizes, int n_in,
                              void* d_out, int out_size, void* d_ws, size_t ws_size,
                              hipStream_t stream) {
    const float* x_coord = (const float*)d_in[0];
    const float* pndata  = (const float*)d_in[1];
    const float* lat     = (const float*)d_in[2];
    const float* W_lift  = (const float*)d_in[3];
    const float* b_lift  = (const float*)d_in[4];
    const float* kW1     = (const float*)d_in[5];
    const float* kb1     = (const float*)d_in[6];
    const float* kW2     = (const float*)d_in[7];
    const float* kb2     = (const float*)d_in[8];
    const float* kW3     = (const float*)d_in[9];
    const float* kb3     = (const float*)d_in[10];
    float* out = (float*)d_out;

    magno_fused<<<B_ * NL_, 256, 0, stream>>>(
        x_coord, lat, kW1, kb1, kW2, kb2, kW3, kb3,
        pndata, W_lift, b_lift, out);
}

// Round 7
// 89.812 us; speedup vs baseline: 1.1595x; 1.1595x over previous
//
#include <hip/hip_runtime.h>

// Problem constants (from reference setup_inputs)
static constexpr int B_ = 2, N_ = 2048, NL_ = 512, IN_C_ = 16, C_ = 32, H_ = 32;
static constexpr float R1SQ = (float)(0.07 * 0.07);   // (RADIUS*1)^2
static constexpr float R2SQ = (float)(0.14 * 0.14);   // (RADIUS*2)^2

typedef __attribute__((ext_vector_type(8))) short bf16x8;  // 8 bf16 = 4 VGPRs
typedef __attribute__((ext_vector_type(4))) float f32x4;   // 4 fp32 acc

// jax.nn.gelu(approximate=True) via identity 0.5x(1+tanh(z)) = x*(1 - 1/(exp(2z)+1)).
// v_rcp_f32 (1 ulp) instead of divide: absorbed by bf16 rounding downstream.
__device__ __forceinline__ float gelu_tanh(float x) {
    float z2 = 2.0f * 0.7978845608028654f * x * fmaf(0.044715f * x, x, 1.0f);
    float e = __expf(z2);
    float t = __builtin_amdgcn_rcpf(e + 1.0f);
    return x - x * t;
}

// fp32 -> bf16 bits, round-to-nearest-even (inputs finite)
__device__ __forceinline__ short f2bf(float x) {
    unsigned u = __float_as_uint(x);
    u += 0x7fffu + ((u >> 16) & 1u);
    return (short)(u >> 16);
}

// f = pndata @ W_lift + b_lift   (B*N rows of 16 -> 32)
__global__ __launch_bounds__(256)
void lift_kernel(const float* __restrict__ pnd,
                 const float* __restrict__ Wl, const float* __restrict__ bl,
                 float* __restrict__ f)
{
    __shared__ float sW[IN_C_ * C_];
    __shared__ float sb[C_];
    int tid = threadIdx.x;
    for (int idx = tid; idx < IN_C_ * C_; idx += 256) sW[idx] = Wl[idx];
    if (tid < C_) sb[tid] = bl[tid];
    __syncthreads();
    int c = tid & 31;
    int row = blockIdx.x * 8 + (tid >> 5);
    if (row >= B_ * N_) return;
    const float* p = pnd + (size_t)row * IN_C_;
    float s = sb[c];
#pragma unroll
    for (int m = 0; m < IN_C_; ++m) s = fmaf(p[m], sW[m * C_ + c], s);
    f[(size_t)row * C_ + c] = s;
}

// One block per (b, latent token i). 256 threads = 4 waves.
// Wave-private compaction; Pass B has ZERO block barriers (strans is
// per-wave and LDS ops within a wave are in-order), so the 4 waves are
// fully decoupled until the final reduction barrier.
__global__ __launch_bounds__(256)
void magno_mfma(const float* __restrict__ x_coord,   // (B,N,2)
                const float* __restrict__ lat,        // (NL,2)
                const float* __restrict__ kW1, const float* __restrict__ kb1,
                const float* __restrict__ kW2, const float* __restrict__ kb2,
                const float* __restrict__ kW3, const float* __restrict__ kb3,
                const float* __restrict__ f,          // (B,N,32) fp32
                float* __restrict__ out)              // (B,NL,32)
{
    __shared__ float sW23[2][H_ * H_];                  // staged kW2, kW3
    __shared__ float sR0[H_], sR1[H_], sA1[H_];
    __shared__ unsigned jlist[4][512];                  // per-wave segments
    __shared__ __align__(16) short strans[4][64 * 40];  // per-wave bf16 transpose, pitch 40
    __shared__ float sred[4][C_];
    __shared__ int scnt[4][2];                          // per-wave {n, c1}

    const int tid  = threadIdx.x;
    const int lane = tid & 63;
    const int wid  = tid >> 6;
    const int qd   = lane >> 4;    // quad 0..3
    const int li   = lane & 15;
    const int bi = blockIdx.x;
    const int b = bi >> 9, i = bi & (NL_ - 1);
    const float xq0 = lat[2 * i], xq1 = lat[2 * i + 1];

    // ---- stage W2/W3 coalesced (first use after barrier) ----
    for (int idx = tid; idx < H_ * H_; idx += 256) {
        sW23[0][idx] = kW2[idx];
        sW23[1][idx] = kW3[idx];
    }
    if (tid < H_) {
        sR0[tid] = kW1[tid];
        sR1[tid] = kW1[H_ + tid];
        sA1[tid] = fmaf(xq0, kW1[2 * H_ + tid], fmaf(xq1, kW1[3 * H_ + tid], kb1[tid]));
    }
    const float b2A = kb2[li], b2B = kb2[li + 16];
    const float b3A = kb3[li], b3B = kb3[li + 16];

    // ---- Pass A: wave-private ballot compaction over j in [512*wid, 512*(wid+1)) ----
    const float2* __restrict__ xc = (const float2*)(x_coord + (size_t)b * N_ * 2);
    const unsigned long long ltmask = (1ull << lane) - 1ull;
    float2 ys[8];
#pragma unroll
    for (int t = 0; t < 8; ++t) ys[t] = xc[512 * wid + 64 * t + lane];   // all in flight
    int cnt = 0, c1w = 0;
#pragma unroll
    for (int t = 0; t < 8; ++t) {
        float dy0 = ys[t].x - xq0, dy1 = ys[t].y - xq1;
        float d2 = dy0 * dy0 + dy1 * dy1;
        bool in2 = d2 <= R2SQ;
        bool in1 = d2 <= R1SQ;
        unsigned long long m2 = __ballot(in2);
        unsigned long long m1 = __ballot(in1);
        if (in2) {
            int pos = cnt + __popcll(m2 & ltmask);
            jlist[wid][pos] = (unsigned)(512 * wid + 64 * t + lane) | (in1 ? 0x80000000u : 0u);
        }
        cnt += __popcll(m2);   // wave-uniform
        c1w += __popcll(m1);
    }
    if (lane == 0) { scnt[wid][0] = cnt; scnt[wid][1] = c1w; }
    __syncthreads();   // covers weight staging + scnt publication

    const int n  = scnt[0][0] + scnt[1][0] + scnt[2][0] + scnt[3][0];
    const int c1 = scnt[0][1] + scnt[1][1] + scnt[2][1] + scnt[3][1];
    const float inv2 = 1.0f / (float)(n  > 0 ? n  : 1);
    const float inv1 = 1.0f / (float)(c1 > 0 ? c1 : 1);

    // ---- B-fragments from LDS (strided b32 reads, cheap) ----
    bf16x8 w2f[2], w3f[2];
#pragma unroll
    for (int nt = 0; nt < 2; ++nt) {
        int n0 = li + 16 * nt;
#pragma unroll
        for (int jj = 0; jj < 8; ++jj) {
            int k = qd * 8 + jj;
            w2f[nt][jj] = f2bf(sW23[0][k * H_ + n0]);
            w3f[nt][jj] = f2bf(sW23[1][k * H_ + n0]);
        }
    }

    // layer-1 weight slices for this lane's k-range
    float r0v[8], r1v[8], a1v[8];
#pragma unroll
    for (int jj = 0; jj < 8; ++jj) {
        int k = qd * 8 + jj;
        r0v[jj] = sR0[k]; r1v[jj] = sR1[k]; a1v[jj] = sA1[k];
    }

    short* tb = &strans[wid][0];
    const unsigned* __restrict__ jl = &jlist[wid][0];
    const float* __restrict__ fbase = f + (size_t)b * N_ * C_;

    float accA = 0.0f, accB = 0.0f;   // channels li and li+16

    // ---- Pass B: wave-private loop, no block barriers ----
    for (int base = 0; base < cnt; base += 64) {
        // ---- prefetch f for this wave's 64 entries (hidden under MLP) ----
        float fAv[4][4], fBv[4][4];
#pragma unroll
        for (int mt = 0; mt < 4; ++mt)
#pragma unroll
            for (int r = 0; r < 4; ++r) {
                int el = base + 16 * mt + 4 * qd + r;
                unsigned pk = jl[el & 511];           // safe index
                int j = (int)(pk & (unsigned)(N_ - 1));
                const float* fr = fbase + (size_t)j * C_;
                fAv[mt][r] = fr[li];
                fBv[mt][r] = fr[li + 16];
            }

        // ---- layer 1 directly in A-fragment layout ----
        bf16x8 hfrag[4];
#pragma unroll
        for (int mt = 0; mt < 4; ++mt) {
            int e = base + 16 * mt + li;
            unsigned pk = jl[e & 511];
            int j = (int)(pk & (unsigned)(N_ - 1));
            float2 y = xc[j];   // L1/L2-warm (Pass A read all of xc)
#pragma unroll
            for (int jj = 0; jj < 8; ++jj)
                hfrag[mt][jj] = f2bf(gelu_tanh(fmaf(y.x, r0v[jj], fmaf(y.y, r1v[jj], a1v[jj]))));
        }

        // ---- layer 2 mfma ----
        f32x4 acc2[4][2];
#pragma unroll
        for (int mt = 0; mt < 4; ++mt)
#pragma unroll
            for (int nt = 0; nt < 2; ++nt) {
                f32x4 z = {0.f, 0.f, 0.f, 0.f};
                acc2[mt][nt] = __builtin_amdgcn_mfma_f32_16x16x32_bf16(hfrag[mt], w2f[nt], z, 0, 0, 0);
            }

        // ---- h2 = gelu(acc2+b2) -> bf16 LDS [entry][hidden] (wave-private, in-order DS) ----
#pragma unroll
        for (int mt = 0; mt < 4; ++mt)
#pragma unroll
            for (int nt = 0; nt < 2; ++nt) {
                float bb = nt ? b2B : b2A;
                int hid = li + 16 * nt;
#pragma unroll
                for (int r = 0; r < 4; ++r) {
                    int entry = 16 * mt + 4 * qd + r;
                    tb[entry * 40 + hid] = f2bf(gelu_tanh(acc2[mt][nt][r] + bb));
                }
            }

        // ---- layer 3: A-fragments via b128 read-back, mfma ----
        f32x4 acc3[4][2];
#pragma unroll
        for (int mt = 0; mt < 4; ++mt) {
            bf16x8 h2 = *(const bf16x8*)&tb[(li + 16 * mt) * 40 + qd * 8];
            f32x4 z = {0.f, 0.f, 0.f, 0.f};
            acc3[mt][0] = __builtin_amdgcn_mfma_f32_16x16x32_bf16(h2, w3f[0], z, 0, 0, 0);
            acc3[mt][1] = __builtin_amdgcn_mfma_f32_16x16x32_bf16(h2, w3f[1], z, 0, 0, 0);
        }

        // ---- epilogue: acc_c += w_e * f[j_e][c] * (kv_e[c] + b3[c]) ----
#pragma unroll
        for (int mt = 0; mt < 4; ++mt)
#pragma unroll
            for (int r = 0; r < 4; ++r) {
                int el = base + 16 * mt + 4 * qd + r;
                unsigned pk = jl[el & 511];
                float w = (el < cnt) ? (inv2 + ((pk & 0x80000000u) ? inv1 : 0.0f)) : 0.0f;
                accA = fmaf(w * fAv[mt][r], acc3[mt][0][r] + b3A, accA);
                accB = fmaf(w * fBv[mt][r], acc3[mt][1][r] + b3B, accB);
            }
    }

    // ---- reduce over quads (entries); channels already on lanes ----
    accA += __shfl_xor(accA, 16, 64);
    accA += __shfl_xor(accA, 32, 64);
    accB += __shfl_xor(accB, 16, 64);
    accB += __shfl_xor(accB, 32, 64);
    if (lane < 16) {
        sred[wid][li] = accA;
        sred[wid][li + 16] = accB;
    }
    __syncthreads();
    if (tid < C_)
        out[(size_t)bi * C_ + tid] = (sred[0][tid] + sred[1][tid]) + (sred[2][tid] + sred[3][tid]);
}

extern "C" void kernel_launch(void* const* d_in, const int* in_sizes, int n_in,
                              void* d_out, int out_size, void* d_ws, size_t ws_size,
                              hipStream_t stream) {
    const float* x_coord = (const float*)d_in[0];
    const float* pndata  = (const float*)d_in[1];
    const float* lat     = (const float*)d_in[2];
    const float* W_lift  = (const float*)d_in[3];
    const float* b_lift  = (const float*)d_in[4];
    const float* kW1     = (const float*)d_in[5];
    const float* kb1     = (const float*)d_in[6];
    const float* kW2     = (const float*)d_in[7];
    const float* kb2     = (const float*)d_in[8];
    const float* kW3     = (const float*)d_in[9];
    const float* kb3     = (const float*)d_in[10];
    float* out = (float*)d_out;

    float* f = (float*)d_ws;   // B*N*C fp32 = 512 KB scratch
    lift_kernel<<<(B_ * N_ + 7) / 8, 256, 0, stream>>>(pndata, W_lift, b_lift, f);
    magno_mfma<<<B_ * NL_, 256, 0, stream>>>(
        x_coord, lat, kW1, kb1, kW2, kb2, kW3, kb3, f, out);
}

// Round 8
// 85.507 us; speedup vs baseline: 1.2179x; 1.0504x over previous
//
#include <hip/hip_runtime.h>

// Problem constants (from reference setup_inputs)
static constexpr int B_ = 2, N_ = 2048, NL_ = 512, IN_C_ = 16, C_ = 32, H_ = 32;
static constexpr float R1SQ = (float)(0.07 * 0.07);   // (RADIUS*1)^2
static constexpr float R2SQ = (float)(0.14 * 0.14);   // (RADIUS*2)^2

typedef __attribute__((ext_vector_type(8))) short bf16x8;  // 8 bf16 = 4 VGPRs
typedef __attribute__((ext_vector_type(4))) float f32x4;   // 4 fp32 acc

// jax.nn.gelu(approximate=True) via 0.5x(1+tanh(z)) = x*(1 - 1/(exp(2z)+1)),
// with log2e folded: exp(2z) = exp2(C1*x*(1+0.044715x^2)),
// C1 = 2*sqrt(2/pi)*log2(e). rcp (1 ulp) absorbed by bf16 rounding downstream.
__device__ __forceinline__ float gelu_tanh(float x) {
    float z2 = 2.3022082f * x * fmaf(0.044715f * x, x, 1.0f);
    float e = __builtin_amdgcn_exp2f(z2);
    float t = __builtin_amdgcn_rcpf(e + 1.0f);
    return x - x * t;
}

// fp32 -> bf16 bits, round-to-nearest-even (inputs finite)
__device__ __forceinline__ short f2bf(float x) {
    unsigned u = __float_as_uint(x);
    u += 0x7fffu + ((u >> 16) & 1u);
    return (short)(u >> 16);
}

// f = pndata @ W_lift + b_lift   (B*N rows of 16 -> 32)
__global__ __launch_bounds__(256)
void lift_kernel(const float* __restrict__ pnd,
                 const float* __restrict__ Wl, const float* __restrict__ bl,
                 float* __restrict__ f)
{
    __shared__ float sW[IN_C_ * C_];
    __shared__ float sb[C_];
    int tid = threadIdx.x;
    for (int idx = tid; idx < IN_C_ * C_; idx += 256) sW[idx] = Wl[idx];
    if (tid < C_) sb[tid] = bl[tid];
    __syncthreads();
    int c = tid & 31;
    int row = blockIdx.x * 8 + (tid >> 5);
    if (row >= B_ * N_) return;
    const float* p = pnd + (size_t)row * IN_C_;
    float s = sb[c];
#pragma unroll
    for (int m = 0; m < IN_C_; ++m) s = fmaf(p[m], sW[m * C_ + c], s);
    f[(size_t)row * C_ + c] = s;
}

// One block per (b, latent token i). 256 threads = 4 waves.
// Wave-private compaction; Pass B = one 16-entry M-tile per iteration
// (fine granularity -> minimal padding work), ZERO block barriers inside.
__global__ __launch_bounds__(256)
void magno_mfma(const float* __restrict__ x_coord,   // (B,N,2)
                const float* __restrict__ lat,        // (NL,2)
                const float* __restrict__ kW1, const float* __restrict__ kb1,
                const float* __restrict__ kW2, const float* __restrict__ kb2,
                const float* __restrict__ kW3, const float* __restrict__ kb3,
                const float* __restrict__ f,          // (B,N,32) fp32
                float* __restrict__ out)              // (B,NL,32)
{
    __shared__ float sW23[2][H_ * H_];                  // staged kW2, kW3
    __shared__ float sR0[H_], sR1[H_], sA1[H_];
    __shared__ unsigned jlist[4][512];                  // per-wave segments
    __shared__ __align__(16) short strans[4][16 * 40];  // per-wave bf16 transpose, 16 rows, pitch 40
    __shared__ float sred[4][C_];
    __shared__ int scnt[4][2];                          // per-wave {n, c1}

    const int tid  = threadIdx.x;
    const int lane = tid & 63;
    const int wid  = tid >> 6;
    const int qd   = lane >> 4;    // quad 0..3
    const int li   = lane & 15;
    const int bi = blockIdx.x;
    const int b = bi >> 9, i = bi & (NL_ - 1);
    const float xq0 = lat[2 * i], xq1 = lat[2 * i + 1];

    // ---- stage W2/W3 coalesced (first use after barrier) ----
    for (int idx = tid; idx < H_ * H_; idx += 256) {
        sW23[0][idx] = kW2[idx];
        sW23[1][idx] = kW3[idx];
    }
    if (tid < H_) {
        sR0[tid] = kW1[tid];
        sR1[tid] = kW1[H_ + tid];
        sA1[tid] = fmaf(xq0, kW1[2 * H_ + tid], fmaf(xq1, kW1[3 * H_ + tid], kb1[tid]));
    }
    const float b2A = kb2[li], b2B = kb2[li + 16];
    const float b3A = kb3[li], b3B = kb3[li + 16];

    // ---- Pass A: wave-private ballot compaction over j in [512*wid, 512*(wid+1)) ----
    const float2* __restrict__ xc = (const float2*)(x_coord + (size_t)b * N_ * 2);
    const unsigned long long ltmask = (1ull << lane) - 1ull;
    float2 ys[8];
#pragma unroll
    for (int t = 0; t < 8; ++t) ys[t] = xc[512 * wid + 64 * t + lane];   // all in flight
    int cnt = 0, c1w = 0;
#pragma unroll
    for (int t = 0; t < 8; ++t) {
        float dy0 = ys[t].x - xq0, dy1 = ys[t].y - xq1;
        float d2 = dy0 * dy0 + dy1 * dy1;
        bool in2 = d2 <= R2SQ;
        bool in1 = d2 <= R1SQ;
        unsigned long long m2 = __ballot(in2);
        unsigned long long m1 = __ballot(in1);
        if (in2) {
            int pos = cnt + __popcll(m2 & ltmask);
            jlist[wid][pos] = (unsigned)(512 * wid + 64 * t + lane) | (in1 ? 0x80000000u : 0u);
        }
        cnt += __popcll(m2);   // wave-uniform
        c1w += __popcll(m1);
    }
    if (lane == 0) { scnt[wid][0] = cnt; scnt[wid][1] = c1w; }
    __syncthreads();   // covers weight staging + scnt publication

    const int n  = scnt[0][0] + scnt[1][0] + scnt[2][0] + scnt[3][0];
    const int c1 = scnt[0][1] + scnt[1][1] + scnt[2][1] + scnt[3][1];
    const float inv2 = 1.0f / (float)(n  > 0 ? n  : 1);
    const float inv1 = 1.0f / (float)(c1 > 0 ? c1 : 1);

    // ---- B-fragments from LDS (verified 16x16x32 layout): B[k=qd*8+jj][n=li+16*nt] ----
    bf16x8 w2f[2], w3f[2];
#pragma unroll
    for (int nt = 0; nt < 2; ++nt) {
        int n0 = li + 16 * nt;
#pragma unroll
        for (int jj = 0; jj < 8; ++jj) {
            int k = qd * 8 + jj;
            w2f[nt][jj] = f2bf(sW23[0][k * H_ + n0]);
            w3f[nt][jj] = f2bf(sW23[1][k * H_ + n0]);
        }
    }

    // layer-1 weight slices for this lane's k-range
    float r0v[8], r1v[8], a1v[8];
#pragma unroll
    for (int jj = 0; jj < 8; ++jj) {
        int k = qd * 8 + jj;
        r0v[jj] = sR0[k]; r1v[jj] = sR1[k]; a1v[jj] = sA1[k];
    }

    short* tb = &strans[wid][0];
    const unsigned* __restrict__ jl = &jlist[wid][0];
    const float* __restrict__ fbase = f + (size_t)b * N_ * C_;

    float accA = 0.0f, accB = 0.0f;   // channels li and li+16

    // ---- Pass B: one 16-entry tile per iteration, wave-private, no block barriers ----
    for (int base = 0; base < cnt; base += 16) {
        // f prefetch for epilogue entries el = base + 4*qd + r (hidden under MLP)
        unsigned pks[4];
        float fAv[4], fBv[4];
#pragma unroll
        for (int r = 0; r < 4; ++r) {
            int el = base + 4 * qd + r;
            pks[r] = jl[el & 511];               // safe index; w=0 masks padding
            int j = (int)(pks[r] & (unsigned)(N_ - 1));
            const float* fr = fbase + (size_t)j * C_;
            fAv[r] = fr[li];
            fBv[r] = fr[li + 16];
        }

        // layer 1 directly in A-fragment layout: entry m = base + li
        int jm = (int)(jl[(base + li) & 511] & (unsigned)(N_ - 1));
        float2 y = xc[jm];   // L1/L2-warm (Pass A read all of xc)
        bf16x8 hfrag;
#pragma unroll
        for (int jj = 0; jj < 8; ++jj)
            hfrag[jj] = f2bf(gelu_tanh(fmaf(y.x, r0v[jj], fmaf(y.y, r1v[jj], a1v[jj]))));

        // layer 2 mfma
        f32x4 z = {0.f, 0.f, 0.f, 0.f};
        f32x4 acc2a = __builtin_amdgcn_mfma_f32_16x16x32_bf16(hfrag, w2f[0], z, 0, 0, 0);
        f32x4 acc2b = __builtin_amdgcn_mfma_f32_16x16x32_bf16(hfrag, w2f[1], z, 0, 0, 0);

        // h2 = gelu(acc2+b2) -> bf16 LDS [entry-in-tile][hidden] (wave-private, in-order DS)
#pragma unroll
        for (int r = 0; r < 4; ++r) {
            int row = 4 * qd + r;
            tb[row * 40 + li]      = f2bf(gelu_tanh(acc2a[r] + b2A));
            tb[row * 40 + li + 16] = f2bf(gelu_tanh(acc2b[r] + b2B));
        }

        // layer 3: A-fragment via b128 read-back, mfma
        bf16x8 h2 = *(const bf16x8*)&tb[li * 40 + qd * 8];
        f32x4 acc3a = __builtin_amdgcn_mfma_f32_16x16x32_bf16(h2, w3f[0], z, 0, 0, 0);
        f32x4 acc3b = __builtin_amdgcn_mfma_f32_16x16x32_bf16(h2, w3f[1], z, 0, 0, 0);

        // epilogue: acc_c += w_e * f[j_e][c] * (kv_e[c] + b3[c])
        // D layout: row(entry-in-tile) = 4*qd + r, col(channel) = li (+16)
#pragma unroll
        for (int r = 0; r < 4; ++r) {
            int el = base + 4 * qd + r;
            float w = (el < cnt) ? (inv2 + ((pks[r] & 0x80000000u) ? inv1 : 0.0f)) : 0.0f;
            accA = fmaf(w * fAv[r], acc3a[r] + b3A, accA);
            accB = fmaf(w * fBv[r], acc3b[r] + b3B, accB);
        }
    }

    // ---- reduce over quads (entries); channels already on lanes ----
    accA += __shfl_xor(accA, 16, 64);
    accA += __shfl_xor(accA, 32, 64);
    accB += __shfl_xor(accB, 16, 64);
    accB += __shfl_xor(accB, 32, 64);
    if (lane < 16) {
        sred[wid][li] = accA;
        sred[wid][li + 16] = accB;
    }
    __syncthreads();
    if (tid < C_)
        out[(size_t)bi * C_ + tid] = (sred[0][tid] + sred[1][tid]) + (sred[2][tid] + sred[3][tid]);
}

extern "C" void kernel_launch(void* const* d_in, const int* in_sizes, int n_in,
                              void* d_out, int out_size, void* d_ws, size_t ws_size,
                              hipStream_t stream) {
    const float* x_coord = (const float*)d_in[0];
    const float* pndata  = (const float*)d_in[1];
    const float* lat     = (const float*)d_in[2];
    const float* W_lift  = (const float*)d_in[3];
    const float* b_lift  = (const float*)d_in[4];
    const float* kW1     = (const float*)d_in[5];
    const float* kb1     = (const float*)d_in[6];
    const float* kW2     = (const float*)d_in[7];
    const float* kb2     = (const float*)d_in[8];
    const float* kW3     = (const float*)d_in[9];
    const float* kb3     = (const float*)d_in[10];
    float* out = (float*)d_out;

    float* f = (float*)d_ws;   // B*N*C fp32 = 512 KB scratch
    lift_kernel<<<(B_ * N_ + 7) / 8, 256, 0, stream>>>(pndata, W_lift, b_lift, f);
    magno_mfma<<<B_ * NL_, 256, 0, stream>>>(
        x_coord, lat, kW1, kb1, kW2, kb2, kW3, kb3, f, out);
}